// Round 6
// baseline (386.315 us; speedup 1.0000x reference)
//
#include <hip/hip_runtime.h>

#define SS 512
#define BB 512
#define TT 64
#define FSTRIDE ((size_t)BB * TT)

// One wave (64 lanes) per batch element; lane == target tag j.
// v[j] lives in lane j's register. Candidates are generated in ASCENDING
// source order i = 0..63 via v_readlane broadcast, so strict-'>' tracking
// reproduces the reference's first-occurrence argmax bit-exactly.
// ZERO barriers: wave-synchronous execution; hist ds_write is fire-and-forget.
__global__ __launch_bounds__(64, 1) void viterbi_wave(
    const float* __restrict__ feats,   // (S,B,T)
    const float* __restrict__ mask,    // (B,S)
    const float* __restrict__ startt,  // (T,)
    const float* __restrict__ endt,    // (T,)
    const float* __restrict__ trans,   // (T,T)
    int* __restrict__ out)             // (B,S)
{
    __shared__ unsigned char hist[(SS - 1) * TT];

    const int b    = blockIdx.x;
    const int lane = threadIdx.x;      // target tag j

    // ---- transitions column T[i][j], i = 0..63 (coalesced, L2-resident) ----
    float t[TT];
#pragma unroll
    for (int i = 0; i < TT; ++i) t[i] = trans[i * TT + lane];

    // ---- v0 = start + feats[0] ----
    float v = startt[lane] + feats[(size_t)b * TT + lane];

    // ---- len = sum(mask[b]) (exact 0/1 fp adds), uniform across wave ----
    float msum = 0.f;
#pragma unroll
    for (int k = 0; k < 8; ++k) msum += mask[b * SS + lane + 64 * k];
#pragma unroll
    for (int off = 1; off < 64; off <<= 1) msum += __shfl_xor(msum, off);
    const int len = (int)(msum + 0.5f);

    const float* fb = feats + (size_t)b * TT + lane;   // emission pointer
    unsigned hoff = lane;                               // hist write cursor

    // ---- one Viterbi step: 64 candidates, 4 parallel chains of 16 ----
    auto body = [&](float e) {
        float bc[4]; int xc[4];
#pragma unroll
        for (int c = 0; c < 4; ++c) {
            float sv0 = __int_as_float(
                __builtin_amdgcn_readlane(__float_as_int(v), 16 * c));
            float bb = (sv0 + t[16 * c]) + e;   // reference association
            int   xx = 16 * c;
#pragma unroll
            for (int p = 1; p < 16; ++p) {
                const int i = 16 * c + p;
                float sv = __int_as_float(
                    __builtin_amdgcn_readlane(__float_as_int(v), i));
                float x = (sv + t[i]) + e;
                if (x > bb) { bb = x; xx = i; }   // strict '>': first-max kept
            }
            bc[c] = bb; xc[c] = xx;
        }
        // ordered merge (ascending-i chains): strict '>' keeps earliest i
        float bestv = bc[0]; int bi = xc[0];
        if (bc[1] > bestv) { bestv = bc[1]; bi = xc[1]; }
        if (bc[2] > bestv) { bestv = bc[2]; bi = xc[2]; }
        if (bc[3] > bestv) { bestv = bc[3]; bi = xc[3]; }

        v = bestv;                                 // mask==1 in-loop: new_v = best
        hist[hoff] = (unsigned char)bi;            // ds_write, no wait needed
        hoff += TT;
    };

    // ---- emissions: 8-deep chunked prefetch (static reg indexing) ----
    float ec[8], en[8];
#pragma unroll
    for (int u = 0; u < 8; ++u) {
        int sn = 1 + u; if (sn > SS - 1) sn = SS - 1;
        ec[u] = fb[(size_t)sn * FSTRIDE];
    }

    int s = 1;
    while (s + 8 <= len) {
#pragma unroll
        for (int u = 0; u < 8; ++u) {
            int sn = s + 8 + u; if (sn > SS - 1) sn = SS - 1;
            en[u] = fb[(size_t)sn * FSTRIDE];
        }
#pragma unroll
        for (int u = 0; u < 8; ++u) body(ec[u]);
#pragma unroll
        for (int u = 0; u < 8; ++u) ec[u] = en[u];
        s += 8;
    }
#pragma unroll
    for (int u = 0; u < 7; ++u) {
        if (s + u < len) body(ec[u]);
    }

    // ---- final argmax over tags (lex first-max butterfly) ----
    float fv = v + endt[lane];
    int bix = lane;
#pragma unroll
    for (int off = 1; off < 64; off <<= 1) {
        float ov = __shfl_xor(fv, off);
        int   oi = __shfl_xor(bix, off);
        if (ov > fv || (ov == fv && oi < bix)) { fv = ov; bix = oi; }
    }
    int cur = bix;                      // uniform across wave
    int* ob = out + (size_t)b * SS;

    if (lane == 0) { ob[SS - 1] = cur; ob[len - 1] = cur; }

    // zeros for masked region s in [len, S-2]
    for (int s2 = len + lane; s2 < SS - 1; s2 += TT) ob[s2] = 0;

    // ---- backtrace: row-load + ds_bpermute chase (pipelined by 1) ----
    int rowb = hist[(len - 2) * TT + lane];
    for (int s2 = len - 2; s2 >= 0; --s2) {
        int rown = (s2 > 0) ? hist[(s2 - 1) * TT + lane] : 0;
        cur = __builtin_amdgcn_ds_bpermute(cur << 2, rowb);  // = hist[s2][cur]
        if (lane == 0) ob[s2] = cur;
        rowb = rown;
    }
}

extern "C" void kernel_launch(void* const* d_in, const int* in_sizes, int n_in,
                              void* d_out, int out_size, void* d_ws, size_t ws_size,
                              hipStream_t stream) {
    const float* feats  = (const float*)d_in[0];
    const float* mask   = (const float*)d_in[1];
    const float* startt = (const float*)d_in[2];
    const float* endt   = (const float*)d_in[3];
    const float* trans  = (const float*)d_in[4];
    int* out = (int*)d_out;

    viterbi_wave<<<dim3(BB), dim3(TT), 0, stream>>>(
        feats, mask, startt, endt, trans, out);
}

// Round 7
// 355.120 us; speedup vs baseline: 1.0878x; 1.0878x over previous
//
#include <hip/hip_runtime.h>

#define SS 512
#define BB 512
#define TT 64
#define FSTRIDE ((size_t)BB * TT)

typedef float float2v __attribute__((ext_vector_type(2)));
typedef float float4v __attribute__((ext_vector_type(4)));

// packed f32 add: 2 IEEE adds in 1 VOP3P instruction
__device__ __forceinline__ float2v pk_add(float2v a, float2v b) {
    float2v d;
    asm("v_pk_add_f32 %0, %1, %2" : "=v"(d) : "v"(a), "v"(b));
    return d;
}
// guaranteed v_max3_f32 (exact 3-input max, no vcc)
__device__ __forceinline__ float max3f(float a, float b, float c) {
    float d;
    asm("v_max3_f32 %0, %1, %2, %3" : "=v"(d) : "v"(a), "v"(b), "v"(c));
    return d;
}

// element i (0..63) of a float2v[32] register array (compile-time i)
#define CEL(A, i) ((((i) & 1) == 0) ? (A)[(i) >> 1].x : (A)[(i) >> 1].y)

// One k-slot of the first-max index scan: 4 chains (i = 16c + K) with four
// DISTINCT sgpr-pair masks -> no vcc serialization. Called K=15 down to 0, so
// the last writer on a tie is the smallest index == reference argmax.
template <int K>
__device__ __forceinline__ void scan4(float best, float s0, float s1, float s2,
                                      float s3, int& i0, int& i1, int& i2, int& i3) {
    unsigned long long m0, m1, m2, m3;
    asm("v_cmp_neq_f32 %0, %1, %2" : "=s"(m0) : "v"(s0), "v"(best));
    asm("v_cmp_neq_f32 %0, %1, %2" : "=s"(m1) : "v"(s1), "v"(best));
    asm("v_cmp_neq_f32 %0, %1, %2" : "=s"(m2) : "v"(s2), "v"(best));
    asm("v_cmp_neq_f32 %0, %1, %2" : "=s"(m3) : "v"(s3), "v"(best));
    // d = neq ? keep : K   (src0 = inline const K, allowed in VOP3)
    asm("v_cndmask_b32 %0, %2, %0, %1" : "+v"(i0) : "s"(m0), "n"(K));
    asm("v_cndmask_b32 %0, %2, %0, %1" : "+v"(i1) : "s"(m1), "n"(16 + K));
    asm("v_cndmask_b32 %0, %2, %0, %1" : "+v"(i2) : "s"(m2), "n"(32 + K));
    asm("v_cndmask_b32 %0, %2, %0, %1" : "+v"(i3) : "s"(m3), "n"(48 + K));
}

// One Viterbi step for a single wave. cur holds all 64 v_i (every lane has the
// full vector); lane j uses its own transitions column tc2 and emission e.
// Writes new v to LDS, immediately issues next step's broadcast reads into
// nxt, then does the index scan (hiding the LDS read latency).
__device__ __forceinline__ void vstep(float2v (&cur)[32], float2v (&nxt)[32],
                                      const float2v (&tc2)[32], float e,
                                      float (&vbuf)[TT],
                                      unsigned char (&hist)[(SS - 1) * TT],
                                      unsigned& hoff, int lane, float& vlast) {
    float2v ee; ee.x = e; ee.y = e;
    // sc = (v + T) + e, in place (exact reference association)
#pragma unroll
    for (int q = 0; q < 32; ++q) cur[q] = pk_add(pk_add(cur[q], tc2[q]), ee);

    // exact max via max3 tree: 64 -> 22 -> 8 -> 3 -> 1
    float l1[22];
#pragma unroll
    for (int k = 0; k < 21; ++k)
        l1[k] = max3f(CEL(cur, 3 * k), CEL(cur, 3 * k + 1), CEL(cur, 3 * k + 2));
    l1[21] = CEL(cur, 63);
    float l2[8];
#pragma unroll
    for (int k = 0; k < 7; ++k) l2[k] = max3f(l1[3 * k], l1[3 * k + 1], l1[3 * k + 2]);
    l2[7] = l1[21];
    float l3a = max3f(l2[0], l2[1], l2[2]);
    float l3b = max3f(l2[3], l2[4], l2[5]);
    float l3c = fmaxf(l2[6], l2[7]);
    float best = max3f(l3a, l3b, l3c);

    // publish v_new and immediately issue next step's broadcast reads
    // (same-wave DS ops are pipeline-ordered; data waits are counted lgkmcnt)
    vbuf[lane] = best;
#pragma unroll
    for (int q = 0; q < 16; ++q) {
        float4v f = *(const float4v*)&vbuf[4 * q];
        nxt[2 * q].x     = f.x; nxt[2 * q].y     = f.y;
        nxt[2 * q + 1].x = f.z; nxt[2 * q + 1].y = f.w;
    }

    // first-max index scan over sc (runs while reads return)
    int i0 = 64, i1 = 64, i2 = 64, i3 = 64;
    scan4<15>(best, CEL(cur, 15), CEL(cur, 31), CEL(cur, 47), CEL(cur, 63), i0, i1, i2, i3);
    scan4<14>(best, CEL(cur, 14), CEL(cur, 30), CEL(cur, 46), CEL(cur, 62), i0, i1, i2, i3);
    scan4<13>(best, CEL(cur, 13), CEL(cur, 29), CEL(cur, 45), CEL(cur, 61), i0, i1, i2, i3);
    scan4<12>(best, CEL(cur, 12), CEL(cur, 28), CEL(cur, 44), CEL(cur, 60), i0, i1, i2, i3);
    scan4<11>(best, CEL(cur, 11), CEL(cur, 27), CEL(cur, 43), CEL(cur, 59), i0, i1, i2, i3);
    scan4<10>(best, CEL(cur, 10), CEL(cur, 26), CEL(cur, 42), CEL(cur, 58), i0, i1, i2, i3);
    scan4<9>(best, CEL(cur, 9), CEL(cur, 25), CEL(cur, 41), CEL(cur, 57), i0, i1, i2, i3);
    scan4<8>(best, CEL(cur, 8), CEL(cur, 24), CEL(cur, 40), CEL(cur, 56), i0, i1, i2, i3);
    scan4<7>(best, CEL(cur, 7), CEL(cur, 23), CEL(cur, 39), CEL(cur, 55), i0, i1, i2, i3);
    scan4<6>(best, CEL(cur, 6), CEL(cur, 22), CEL(cur, 38), CEL(cur, 54), i0, i1, i2, i3);
    scan4<5>(best, CEL(cur, 5), CEL(cur, 21), CEL(cur, 37), CEL(cur, 53), i0, i1, i2, i3);
    scan4<4>(best, CEL(cur, 4), CEL(cur, 20), CEL(cur, 36), CEL(cur, 52), i0, i1, i2, i3);
    scan4<3>(best, CEL(cur, 3), CEL(cur, 19), CEL(cur, 35), CEL(cur, 51), i0, i1, i2, i3);
    scan4<2>(best, CEL(cur, 2), CEL(cur, 18), CEL(cur, 34), CEL(cur, 50), i0, i1, i2, i3);
    scan4<1>(best, CEL(cur, 1), CEL(cur, 17), CEL(cur, 33), CEL(cur, 49), i0, i1, i2, i3);
    scan4<0>(best, CEL(cur, 0), CEL(cur, 16), CEL(cur, 32), CEL(cur, 48), i0, i1, i2, i3);
    int bi = i0;
    if (i1 < bi) bi = i1;
    if (i2 < bi) bi = i2;
    if (i3 < bi) bi = i3;   // chains cover disjoint ascending ranges

    hist[hoff] = (unsigned char)bi;
    hoff += TT;
    vlast = best;
}

__global__ __launch_bounds__(TT, 1) void viterbi_wave(
    const float* __restrict__ feats,   // (S,B,T)
    const float* __restrict__ mask,    // (B,S)
    const float* __restrict__ startt,  // (T,)
    const float* __restrict__ endt,    // (T,)
    const float* __restrict__ trans,   // (T,T)
    int* __restrict__ out)             // (B,S)
{
    __shared__ float vbuf[TT];
    __shared__ unsigned char hist[(SS - 1) * TT];

    const int b    = blockIdx.x;
    const int lane = threadIdx.x;      // target tag j

    // transitions column T[i][lane] as pairs over i
    float2v tc2[32];
#pragma unroll
    for (int q = 0; q < 32; ++q) {
        float2v t;
        t.x = trans[(2 * q) * TT + lane];
        t.y = trans[(2 * q + 1) * TT + lane];
        tc2[q] = t;
    }

    // len = sum(mask[b]) (exact 0/1 adds), uniform after butterfly
    float msum = 0.f;
#pragma unroll
    for (int k = 0; k < 8; ++k) msum += mask[b * SS + lane + 64 * k];
#pragma unroll
    for (int off = 1; off < 64; off <<= 1) msum += __shfl_xor(msum, off);
    const int len = (int)(msum + 0.5f);

    // v0 = start + feats[0]; publish and broadcast-load into vA
    float vlast = startt[lane] + feats[(size_t)b * TT + lane];
    vbuf[lane] = vlast;
    float2v vA[32], vB[32];
#pragma unroll
    for (int q = 0; q < 16; ++q) {
        float4v f = *(const float4v*)&vbuf[4 * q];
        vA[2 * q].x     = f.x; vA[2 * q].y     = f.y;
        vA[2 * q + 1].x = f.z; vA[2 * q + 1].y = f.w;
    }

    const float* fb = feats + (size_t)b * TT + lane;
    unsigned hoff = lane;

    // emissions: 8-deep chunked prefetch
    float ec[8], en[8];
#pragma unroll
    for (int u = 0; u < 8; ++u) ec[u] = fb[(size_t)(1 + u) * FSTRIDE];

    int s = 1;
    while (s + 8 <= len) {
#pragma unroll
        for (int u = 0; u < 8; ++u) {
            int sn = s + 8 + u; if (sn > SS - 1) sn = SS - 1;
            en[u] = fb[(size_t)sn * FSTRIDE];
        }
        vstep(vA, vB, tc2, ec[0], vbuf, hist, hoff, lane, vlast);
        vstep(vB, vA, tc2, ec[1], vbuf, hist, hoff, lane, vlast);
        vstep(vA, vB, tc2, ec[2], vbuf, hist, hoff, lane, vlast);
        vstep(vB, vA, tc2, ec[3], vbuf, hist, hoff, lane, vlast);
        vstep(vA, vB, tc2, ec[4], vbuf, hist, hoff, lane, vlast);
        vstep(vB, vA, tc2, ec[5], vbuf, hist, hoff, lane, vlast);
        vstep(vA, vB, tc2, ec[6], vbuf, hist, hoff, lane, vlast);
        vstep(vB, vA, tc2, ec[7], vbuf, hist, hoff, lane, vlast);
#pragma unroll
        for (int u = 0; u < 8; ++u) ec[u] = en[u];
        s += 8;
    }
    // tail (s stays ≡ 1 mod 8 -> parity of u selects buffer)
    if (s + 0 < len) vstep(vA, vB, tc2, ec[0], vbuf, hist, hoff, lane, vlast);
    if (s + 1 < len) vstep(vB, vA, tc2, ec[1], vbuf, hist, hoff, lane, vlast);
    if (s + 2 < len) vstep(vA, vB, tc2, ec[2], vbuf, hist, hoff, lane, vlast);
    if (s + 3 < len) vstep(vB, vA, tc2, ec[3], vbuf, hist, hoff, lane, vlast);
    if (s + 4 < len) vstep(vA, vB, tc2, ec[4], vbuf, hist, hoff, lane, vlast);
    if (s + 5 < len) vstep(vB, vA, tc2, ec[5], vbuf, hist, hoff, lane, vlast);
    if (s + 6 < len) vstep(vA, vB, tc2, ec[6], vbuf, hist, hoff, lane, vlast);

    // final argmax over tags (lex first-max butterfly)
    float fv = vlast + endt[lane];
    int bix = lane;
#pragma unroll
    for (int off = 1; off < 64; off <<= 1) {
        float ov = __shfl_xor(fv, off);
        int   oi = __shfl_xor(bix, off);
        if (ov > fv || (ov == fv && oi < bix)) { fv = ov; bix = oi; }
    }
    int cur = bix;                      // uniform across wave
    int* ob = out + (size_t)b * SS;

    if (lane == 0) { ob[SS - 1] = cur; ob[len - 1] = cur; }

    // zeros for masked region s in [len, S-2]
    for (int s2 = len + lane; s2 < SS - 1; s2 += TT) ob[s2] = 0;

    // backtrace: row-load + ds_bpermute chase (pipelined by 1)
    int rowb = hist[(len - 2) * TT + lane];
    for (int s2 = len - 2; s2 >= 0; --s2) {
        int rown = (s2 > 0) ? hist[(s2 - 1) * TT + lane] : 0;
        cur = __builtin_amdgcn_ds_bpermute(cur << 2, rowb);  // = hist[s2][cur]
        if (lane == 0) ob[s2] = cur;
        rowb = rown;
    }
}

extern "C" void kernel_launch(void* const* d_in, const int* in_sizes, int n_in,
                              void* d_out, int out_size, void* d_ws, size_t ws_size,
                              hipStream_t stream) {
    const float* feats  = (const float*)d_in[0];
    const float* mask   = (const float*)d_in[1];
    const float* startt = (const float*)d_in[2];
    const float* endt   = (const float*)d_in[3];
    const float* trans  = (const float*)d_in[4];
    int* out = (int*)d_out;

    viterbi_wave<<<dim3(BB), dim3(TT), 0, stream>>>(
        feats, mask, startt, endt, trans, out);
}

// Round 8
// 320.309 us; speedup vs baseline: 1.2061x; 1.1087x over previous
//
#include <hip/hip_runtime.h>

#define SS 512
#define BB 512
#define TT 64
#define FSTRIDE ((size_t)BB * TT)

typedef float float2v __attribute__((ext_vector_type(2)));

// element q (0..63) of a float2v[32] register array (q must be compile-time)
#define EL(A, q) ((((q) & 1) == 0) ? (A)[(q) >> 1].x : (A)[(q) >> 1].y)

// One wave (64 lanes) per batch element; lane == target tag j.
// Zero barriers, zero inline asm: single-wave lockstep makes the per-step
// LDS publish/broadcast safe (same-wave DS ops are pipe-ordered; validated
// R6/R7 absmax=0), and plain C leaves the scheduler free to interleave the
// broadcast ds_read_b128s with the 128-op index scan.
__global__ __launch_bounds__(TT, 1) void viterbi_wave(
    const float* __restrict__ feats,   // (S,B,T)
    const float* __restrict__ mask,    // (B,S)
    const float* __restrict__ startt,  // (T,)
    const float* __restrict__ endt,    // (T,)
    const float* __restrict__ trans,   // (T,T)
    int* __restrict__ out)             // (B,S)
{
    __shared__ float vbuf[TT];
    __shared__ unsigned char hist[(SS - 1) * TT];

    const int b    = blockIdx.x;
    const int lane = threadIdx.x;      // target tag j

    // transitions column T[i][lane] as pairs over i (64 VGPRs, loop-invariant)
    float2v tc2[32];
#pragma unroll
    for (int q = 0; q < 32; ++q) {
        float2v t;
        t.x = trans[(2 * q) * TT + lane];
        t.y = trans[(2 * q + 1) * TT + lane];
        tc2[q] = t;
    }

    // len = sum(mask[b]) (exact 0/1 adds), uniform after butterfly
    float msum = 0.f;
#pragma unroll
    for (int k = 0; k < 8; ++k) msum += mask[b * SS + lane + 64 * k];
#pragma unroll
    for (int off = 1; off < 64; off <<= 1) msum += __shfl_xor(msum, off);
    const int len = (int)(msum + 0.5f);

    // v0 = start + feats[0]; publish and broadcast-load into vA
    float vlast = startt[lane] + feats[(size_t)b * TT + lane];
    vbuf[lane] = vlast;
    float2v vA[32], vB[32];

    auto loadv = [&](float2v(&dst)[32]) {
#pragma unroll
        for (int q = 0; q < 16; ++q) {
            float4 f = *(const float4*)&vbuf[4 * q];   // ds_read_b128 broadcast
            float2v a; a.x = f.x; a.y = f.y; dst[2 * q]     = a;
            float2v c; c.x = f.z; c.y = f.w; dst[2 * q + 1] = c;
        }
    };
    loadv(vA);

    const float* fb = feats + (size_t)b * TT + lane;
    unsigned hoff = lane;

    // One Viterbi step. cur holds the current v replicated (all 64 values in
    // every lane); computes sc = (v+T)+e in place, exact max via fmaxf tree
    // (clang fuses to v_max3_f32), publishes new v, issues next broadcast
    // reads, then runs the first-max index scan (hides the LDS latency).
    auto vstep = [&](float2v(&cur)[32], float2v(&nxt)[32], float e) {
        float2v ee; ee.x = e; ee.y = e;
#pragma unroll
        for (int q = 0; q < 32; ++q) cur[q] = (cur[q] + tc2[q]) + ee;

        // exact max tree: 64 -> 22 -> 8 -> 3 -> 1 (fp max is rounding-free)
        float l1[22];
#pragma unroll
        for (int k = 0; k < 21; ++k)
            l1[k] = fmaxf(fmaxf(EL(cur, 3 * k), EL(cur, 3 * k + 1)), EL(cur, 3 * k + 2));
        l1[21] = EL(cur, 63);
        float l2[8];
#pragma unroll
        for (int k = 0; k < 7; ++k)
            l2[k] = fmaxf(fmaxf(l1[3 * k], l1[3 * k + 1]), l1[3 * k + 2]);
        l2[7] = l1[21];
        float l3a = fmaxf(fmaxf(l2[0], l2[1]), l2[2]);
        float l3b = fmaxf(fmaxf(l2[3], l2[4]), l2[5]);
        float best = fmaxf(fmaxf(l3a, l3b), fmaxf(l2[6], l2[7]));

        // publish v_new; immediately issue next step's broadcast reads
        vbuf[lane] = best;
        loadv(nxt);

        // first-max index: 4 chains, descending k, last writer = smallest
        // index; '==' against the exact max reproduces the reference's
        // first-occurrence argmax bit-exactly.
        int i0 = 64, i1 = 64, i2 = 64, i3 = 64;
#pragma unroll
        for (int k = 15; k >= 0; --k) {
            if (EL(cur, k)      == best) i0 = k;
            if (EL(cur, 16 + k) == best) i1 = 16 + k;
            if (EL(cur, 32 + k) == best) i2 = 32 + k;
            if (EL(cur, 48 + k) == best) i3 = 48 + k;
        }
        int bi = min(min(i0, i1), min(i2, i3));   // disjoint ascending ranges

        hist[hoff] = (unsigned char)bi;
        hoff += TT;
        vlast = best;
    };

    // emissions: 8-deep chunked prefetch (static reg indexing)
    float ec[8], en[8];
#pragma unroll
    for (int u = 0; u < 8; ++u) ec[u] = fb[(size_t)(1 + u) * FSTRIDE];

    int s = 1;
    while (s + 8 <= len) {
#pragma unroll
        for (int u = 0; u < 8; ++u) {
            int sn = s + 8 + u; if (sn > SS - 1) sn = SS - 1;
            en[u] = fb[(size_t)sn * FSTRIDE];
        }
        vstep(vA, vB, ec[0]);
        vstep(vB, vA, ec[1]);
        vstep(vA, vB, ec[2]);
        vstep(vB, vA, ec[3]);
        vstep(vA, vB, ec[4]);
        vstep(vB, vA, ec[5]);
        vstep(vA, vB, ec[6]);
        vstep(vB, vA, ec[7]);
#pragma unroll
        for (int u = 0; u < 8; ++u) ec[u] = en[u];
        s += 8;
    }
    // tail (s ≡ 1 mod 8, so parity of u selects the buffer)
    if (s + 0 < len) vstep(vA, vB, ec[0]);
    if (s + 1 < len) vstep(vB, vA, ec[1]);
    if (s + 2 < len) vstep(vA, vB, ec[2]);
    if (s + 3 < len) vstep(vB, vA, ec[3]);
    if (s + 4 < len) vstep(vA, vB, ec[4]);
    if (s + 5 < len) vstep(vB, vA, ec[5]);
    if (s + 6 < len) vstep(vA, vB, ec[6]);

    // final argmax over tags (lex first-max butterfly)
    float fv = vlast + endt[lane];
    int bix = lane;
#pragma unroll
    for (int off = 1; off < 64; off <<= 1) {
        float ov = __shfl_xor(fv, off);
        int   oi = __shfl_xor(bix, off);
        if (ov > fv || (ov == fv && oi < bix)) { fv = ov; bix = oi; }
    }
    int cur = bix;                      // uniform across wave
    int* ob = out + (size_t)b * SS;

    if (lane == 0) { ob[SS - 1] = cur; ob[len - 1] = cur; }

    // zeros for masked region s in [len, S-2]
    for (int s2 = len + lane; s2 < SS - 1; s2 += TT) ob[s2] = 0;

    // backtrace: row-load + ds_bpermute chase (pipelined by 1)
    int rowb = hist[(len - 2) * TT + lane];
    for (int s2 = len - 2; s2 >= 0; --s2) {
        int rown = (s2 > 0) ? hist[(s2 - 1) * TT + lane] : 0;
        cur = __builtin_amdgcn_ds_bpermute(cur << 2, rowb);  // = hist[s2][cur]
        if (lane == 0) ob[s2] = cur;
        rowb = rown;
    }
}

extern "C" void kernel_launch(void* const* d_in, const int* in_sizes, int n_in,
                              void* d_out, int out_size, void* d_ws, size_t ws_size,
                              hipStream_t stream) {
    const float* feats  = (const float*)d_in[0];
    const float* mask   = (const float*)d_in[1];
    const float* startt = (const float*)d_in[2];
    const float* endt   = (const float*)d_in[3];
    const float* trans  = (const float*)d_in[4];
    int* out = (int*)d_out;

    viterbi_wave<<<dim3(BB), dim3(TT), 0, stream>>>(
        feats, mask, startt, endt, trans, out);
}